// Round 7
// baseline (189.905 us; speedup 1.0000x reference)
//
#include <hip/hip_runtime.h>
#include <hip/hip_bf16.h>

// XDeepFM CIN fused 2-layer MFMA kernel, gfx950 — v7.
// v6 + (a) 3-deep B-staging ring with counted vmcnt(1) + raw s_barrier (no vm
// drain in the K-loops), (b) layer-0 K repacked k = i*40 + j (K=1600, 100
// slices, was 1920/120). 4 waves x 64 rows, 512 blocks, 2 blocks/CU.
// Layer 0: K = 40i x 40j = 1600 (100 K16-slices). Layer 1: K = 39i x 64j = 2496 (156).

using short8 = __attribute__((ext_vector_type(8))) short;
using f32x16 = __attribute__((ext_vector_type(16))) float;

#define VS 56                           // bf16 per V row (112B pitch, 16B-aligned)
#define V_BYTES (256 * VS * 2)          // 28672
#define HS 72                           // bf16 per H row (144B pitch, 16B-aligned)
#define H_BYTES (256 * HS * 2)          // 36864
#define BB_OFF (V_BYTES + H_BYTES)      // 65536
#define SMEM_BYTES (BB_OFF + 3 * 4096)  // 77824 -> 2 blocks/CU

#define NSL0 100                        // layer-0 K16 slices (1600/16)
#define NSL1 156                        // layer-1 K16 slices (2496/16)
#define NSL  (NSL0 + NSL1)              // 256
#define NFRAG (NSL * 256)               // 65536 16B fragments = 1.0 MB

__device__ __forceinline__ unsigned short f2bf(float x) {
  __hip_bfloat16 h = __float2bfloat16(x);
  return __builtin_bit_cast(unsigned short, h);
}
__device__ __forceinline__ unsigned cvt2(float lo, float hi) {
  unsigned r;
  asm("v_cvt_pk_bf16_f32 %0, %1, %2" : "=v"(r) : "v"(lo), "v"(hi));
  return r;
}
__device__ __forceinline__ float bf_lo(unsigned w) {
  return __builtin_bit_cast(float, w << 16);
}
__device__ __forceinline__ float bf_hi(unsigned w) {
  return __builtin_bit_cast(float, w & 0xffff0000u);
}
__device__ __forceinline__ float bf2f(unsigned short b) {
  return __builtin_bit_cast(float, ((unsigned)b) << 16);
}
__device__ __forceinline__ short8 mk_a(float vi, uint4 p) {
  uint4 pk;
  pk.x = cvt2(vi * bf_lo(p.x), vi * bf_hi(p.x));
  pk.y = cvt2(vi * bf_lo(p.y), vi * bf_hi(p.y));
  pk.z = cvt2(vi * bf_lo(p.z), vi * bf_hi(p.z));
  pk.w = cvt2(vi * bf_lo(p.w), vi * bf_hi(p.w));
  return __builtin_bit_cast(short8, pk);
}
__device__ __forceinline__ void stage16(const void* g, char* l) {
  __builtin_amdgcn_global_load_lds((const __attribute__((address_space(1))) void*)g,
                                   (__attribute__((address_space(3))) void*)l, 16, 0, 0);
}

// ---------------- W pre-pack: one 32x32x16 B-fragment per thread ----------------
// Fragment (slice s, n-block nb): lane l holds W[k = 16s + (l>>5)*8 + ii][n = nb*32 + (l&31)].
__global__ void pack_w(const float* __restrict__ W0, const float* __restrict__ W1,
                       short8* __restrict__ wpk) {
  int fid = blockIdx.x * 256 + threadIdx.x;
  if (fid >= NFRAG) return;
  int lane = fid & 63;
  int t2 = fid >> 6;
  int nb = t2 & 3, s = t2 >> 2;
  int n = nb * 32 + (lane & 31);
  int kb = (lane >> 5) * 8;
  short8 frag;
  #pragma unroll
  for (int ii = 0; ii < 8; ii++) {
    float val;
    if (s < NSL0) {                     // layer 0: k = i*40 + j, i,j in [0,40) (39 = pad)
      int k = s * 16 + kb + ii;
      int i = k / 40, j = k - i * 40;
      val = (i < 39 && j < 39) ? W0[(i * 39 + j) * 128 + n] : 0.f;
    } else {                            // layer 1: k = i*64 + j, exact
      int k = (s - NSL0) * 16 + kb + ii;
      int i = k >> 6, j = k & 63;
      val = W1[(i * 64 + j) * 128 + n];
    }
    frag[ii] = (short)f2bf(val);
  }
  wpk[fid] = frag;
}

// ---------------- fused CIN main kernel ----------------
__global__ __launch_bounds__(256, 2) void cin_main(const float* __restrict__ X,
                                                   const short8* __restrict__ wpk,
                                                   float* __restrict__ out) {
  extern __shared__ char smem[];
  unsigned short* Vb = (unsigned short*)smem;             // [256][56] bf16
  unsigned short* H  = (unsigned short*)(smem + V_BYTES); // [256][72] bf16
  char* Bsm          = smem + BB_OFF;                     // 3 x 4KB staging ring

  const int t    = threadIdx.x;
  const int lane = t & 63;
  const int w    = t >> 6;               // wave: rows [w*64, w*64+64)
  const int l31  = lane & 31, hi = lane >> 5;
  const int b0   = blockIdx.x * 16;
  const char* wpkc = (const char*)wpk;
  const int stoff = (w * 64 + lane) * 16;  // this lane's byte offset within a slice

  // prologue: stage slices 0,1 into ring slots 0,1 (drained by the syncthreads below)
  stage16(wpkc + 0 * 4096 + stoff, Bsm + 0 * 4096 + (w << 10));
  stage16(wpkc + 1 * 4096 + stoff, Bsm + 1 * 4096 + (w << 10));

  // ---- stage x: x[b0+bl, i, d] -> Vb[bl*16+d][i] (bf16); cols 39..55 zeroed ----
  const float* xb = X + (size_t)b0 * 624;   // 16*39*16 = 9984 floats
  for (int f = t * 4; f < 9984; f += 1024) {
    float4 v4 = *(const float4*)(xb + f);
    int bl = f / 624;
    int rem = f - bl * 624;
    int i = rem >> 4, d0 = rem & 15;
    int r = bl * 16 + d0;
    Vb[(r + 0) * VS + i] = f2bf(v4.x);
    Vb[(r + 1) * VS + i] = f2bf(v4.y);
    Vb[(r + 2) * VS + i] = f2bf(v4.z);
    Vb[(r + 3) * VS + i] = f2bf(v4.w);
  }
  #pragma unroll
  for (int c = 39; c < VS; c++) Vb[t * VS + c] = 0;
  __syncthreads();   // V ready; stages 0,1 landed for ALL waves (full drain, once)

  const int row0 = w * 64 + l31;
  const int row1 = row0 + 32;
  const int hi8  = 8 * hi;

  // layer-0 per-lane A-gen caches: window j0(rr) = (16rr + 8hi) % 40, i_off(rr) = (16rr+8hi)/40
  uint4 vpe0[5], vpe1[5];
  #pragma unroll
  for (int rr = 0; rr < 5; rr++) {
    int j0 = (16 * rr + hi8) % 40;
    vpe0[rr] = *(const uint4*)(Vb + row0 * VS + j0);
    vpe1[rr] = *(const uint4*)(Vb + row1 * VS + j0);
  }

  f32x16 acc[2][4];
  #pragma unroll
  for (int mi = 0; mi < 2; mi++)
    #pragma unroll
    for (int nb = 0; nb < 4; nb++)
      #pragma unroll
      for (int e = 0; e < 16; e++) acc[mi][nb][e] = 0.f;

  // ================= layer 0: 20 macro-steps x 5 slices (K=1600) =================
  int sg = 0, bcur = 0;   // bcur = sg % 3
  #pragma unroll 1
  for (int m = 0; m < 20; m++) {
    float viA0 = bf2f(Vb[row0 * VS + 2 * m]);
    float viB0 = bf2f(Vb[row0 * VS + 2 * m + 1]);
    float viA1 = bf2f(Vb[row1 * VS + 2 * m]);
    float viB1 = bf2f(Vb[row1 * VS + 2 * m + 1]);
    #pragma unroll
    for (int rr = 0; rr < 5; rr++) {
      int bst = bcur + 2; if (bst >= 3) bst -= 3;
      stage16(wpkc + (size_t)(sg + 2) * 4096 + stoff, Bsm + (bst << 12) + (w << 10));
      const char* bb = Bsm + (bcur << 12) + (lane << 4);
      short8 bf0 = *(const short8*)(bb + 0);
      short8 bf1 = *(const short8*)(bb + 1024);
      short8 bf2 = *(const short8*)(bb + 2048);
      short8 bf3 = *(const short8*)(bb + 3072);
      // vi select: rr 0,1 -> i=2m; rr 3,4 -> i=2m+1; rr=2 -> hi ? 2m+1 : 2m
      float vi0 = (rr < 2) ? viA0 : (rr > 2) ? viB0 : (hi ? viB0 : viA0);
      float vi1 = (rr < 2) ? viA1 : (rr > 2) ? viB1 : (hi ? viB1 : viA1);
      short8 a0 = mk_a(vi0, vpe0[rr]);
      short8 a1 = mk_a(vi1, vpe1[rr]);
      acc[0][0] = __builtin_amdgcn_mfma_f32_32x32x16_bf16(a0, bf0, acc[0][0], 0, 0, 0);
      acc[1][0] = __builtin_amdgcn_mfma_f32_32x32x16_bf16(a1, bf0, acc[1][0], 0, 0, 0);
      acc[0][1] = __builtin_amdgcn_mfma_f32_32x32x16_bf16(a0, bf1, acc[0][1], 0, 0, 0);
      acc[1][1] = __builtin_amdgcn_mfma_f32_32x32x16_bf16(a1, bf1, acc[1][1], 0, 0, 0);
      acc[0][2] = __builtin_amdgcn_mfma_f32_32x32x16_bf16(a0, bf2, acc[0][2], 0, 0, 0);
      acc[1][2] = __builtin_amdgcn_mfma_f32_32x32x16_bf16(a1, bf2, acc[1][2], 0, 0, 0);
      acc[0][3] = __builtin_amdgcn_mfma_f32_32x32x16_bf16(a0, bf3, acc[0][3], 0, 0, 0);
      acc[1][3] = __builtin_amdgcn_mfma_f32_32x32x16_bf16(a1, bf3, acc[1][3], 0, 0, 0);
      // end of slice: own stage(sg+1) landed -> barrier => everyone's sg+1 landed,
      // and all waves done reading buf[sg%3] (reads consumed by the MFMAs above).
      asm volatile("s_waitcnt vmcnt(1)" ::: "memory");
      __builtin_amdgcn_sched_barrier(0);
      __builtin_amdgcn_s_barrier();
      __builtin_amdgcn_sched_barrier(0);
      sg++; bcur = bcur + 1 == 3 ? 0 : bcur + 1;
    }
  }

  // ---- layer-0 epilogue ----
  // C/D layout (HW-verified): col = lane&31, rowtile = (r&3) + 8*(r>>2) + 4*hi.
  #pragma unroll
  for (int mi = 0; mi < 2; mi++)
    #pragma unroll
    for (int nb = 0; nb < 2; nb++)
      #pragma unroll
      for (int r = 0; r < 16; r++) {
        int rt = (r & 3) + 8 * (r >> 2) + 4 * hi;
        H[(w * 64 + mi * 32 + rt) * HS + nb * 32 + l31] = f2bf(fmaxf(acc[mi][nb][r], 0.f));
      }
  #pragma unroll
  for (int mi = 0; mi < 2; mi++)
    #pragma unroll
    for (int nb = 2; nb < 4; nb++) {
      float s0 = 0.f, s1 = 0.f;
      #pragma unroll
      for (int r = 0; r < 8; r++)  s0 += fmaxf(acc[mi][nb][r], 0.f);
      #pragma unroll
      for (int r = 8; r < 16; r++) s1 += fmaxf(acc[mi][nb][r], 0.f);
      s0 += __shfl_xor(s0, 32);
      s1 += __shfl_xor(s1, 32);
      out[(size_t)(b0 + 4 * w + 2 * mi + hi) * 192 + (nb - 2) * 32 + l31] = hi ? s1 : s0;
    }
  __syncthreads();   // H ready (also re-establishes staging invariant: all <= sg+1 landed)

  // layer-1 A-gen caches: window j0(rr) = 16rr + 8hi (H rows are own-wave rows)
  uint4 hp0[4], hp1[4];
  #pragma unroll
  for (int rr = 0; rr < 4; rr++) {
    hp0[rr] = *(const uint4*)(H + row0 * HS + 16 * rr + hi8);
    hp1[rr] = *(const uint4*)(H + row1 * HS + 16 * rr + hi8);
  }

  #pragma unroll
  for (int mi = 0; mi < 2; mi++)
    #pragma unroll
    for (int nb = 0; nb < 4; nb++)
      #pragma unroll
      for (int e = 0; e < 16; e++) acc[mi][nb][e] = 0.f;

  // ================= layer 1: 39 i-groups x 4 slices (K=2496) =================
  #pragma unroll 1
  for (int ig = 0; ig < 39; ig++) {
    float vi0 = bf2f(Vb[row0 * VS + ig]);
    float vi1 = bf2f(Vb[row1 * VS + ig]);
    #pragma unroll
    for (int rr = 0; rr < 4; rr++) {
      int bst = bcur + 2; if (bst >= 3) bst -= 3;
      if (sg + 2 < NSL)
        stage16(wpkc + (size_t)(sg + 2) * 4096 + stoff, Bsm + (bst << 12) + (w << 10));
      const char* bb = Bsm + (bcur << 12) + (lane << 4);
      short8 bf0 = *(const short8*)(bb + 0);
      short8 bf1 = *(const short8*)(bb + 1024);
      short8 bf2 = *(const short8*)(bb + 2048);
      short8 bf3 = *(const short8*)(bb + 3072);
      short8 a0 = mk_a(vi0, hp0[rr]);
      short8 a1 = mk_a(vi1, hp1[rr]);
      acc[0][0] = __builtin_amdgcn_mfma_f32_32x32x16_bf16(a0, bf0, acc[0][0], 0, 0, 0);
      acc[1][0] = __builtin_amdgcn_mfma_f32_32x32x16_bf16(a1, bf0, acc[1][0], 0, 0, 0);
      acc[0][1] = __builtin_amdgcn_mfma_f32_32x32x16_bf16(a0, bf1, acc[0][1], 0, 0, 0);
      acc[1][1] = __builtin_amdgcn_mfma_f32_32x32x16_bf16(a1, bf1, acc[1][1], 0, 0, 0);
      acc[0][2] = __builtin_amdgcn_mfma_f32_32x32x16_bf16(a0, bf2, acc[0][2], 0, 0, 0);
      acc[1][2] = __builtin_amdgcn_mfma_f32_32x32x16_bf16(a1, bf2, acc[1][2], 0, 0, 0);
      acc[0][3] = __builtin_amdgcn_mfma_f32_32x32x16_bf16(a0, bf3, acc[0][3], 0, 0, 0);
      acc[1][3] = __builtin_amdgcn_mfma_f32_32x32x16_bf16(a1, bf3, acc[1][3], 0, 0, 0);
      asm volatile("s_waitcnt vmcnt(1)" ::: "memory");
      __builtin_amdgcn_sched_barrier(0);
      __builtin_amdgcn_s_barrier();
      __builtin_amdgcn_sched_barrier(0);
      sg++; bcur = bcur + 1 == 3 ? 0 : bcur + 1;
    }
  }

  // ---- layer-1 epilogue: relu, sum over d, out[b, 64:192] ----
  #pragma unroll
  for (int mi = 0; mi < 2; mi++)
    #pragma unroll
    for (int nb = 0; nb < 4; nb++) {
      float s0 = 0.f, s1 = 0.f;
      #pragma unroll
      for (int r = 0; r < 8; r++)  s0 += fmaxf(acc[mi][nb][r], 0.f);
      #pragma unroll
      for (int r = 8; r < 16; r++) s1 += fmaxf(acc[mi][nb][r], 0.f);
      s0 += __shfl_xor(s0, 32);
      s1 += __shfl_xor(s1, 32);
      out[(size_t)(b0 + 4 * w + 2 * mi + hi) * 192 + 64 + nb * 32 + l31] = hi ? s1 : s0;
    }
}

extern "C" void kernel_launch(void* const* d_in, const int* in_sizes, int n_in,
                              void* d_out, int out_size, void* d_ws, size_t ws_size,
                              hipStream_t stream) {
  (void)in_sizes; (void)n_in; (void)out_size; (void)ws_size;
  const float* X  = (const float*)d_in[0];   // [8192,39,16]
  const float* W0 = (const float*)d_in[1];   // [1521,128]
  const float* W1 = (const float*)d_in[2];   // [2496,128]
  float* out = (float*)d_out;                // [8192,192]
  short8* wpk = (short8*)d_ws;               // packed bf16 W0|W1, 1.0 MB

  (void)hipFuncSetAttribute((const void*)cin_main,
                            hipFuncAttributeMaxDynamicSharedMemorySize, SMEM_BYTES);

  pack_w<<<(NFRAG + 255) / 256, 256, 0, stream>>>(W0, W1, wpk);
  cin_main<<<512, 256, SMEM_BYTES, stream>>>(X, wpk, out);
}